// Round 1
// baseline (855.053 us; speedup 1.0000x reference)
//
#include <hip/hip_runtime.h>

#define F_LOC 25088
#define CDIM 512
#define VN 6
#define MN 160      // B*T
#define HWN 49
#define NCLS 8

typedef __attribute__((ext_vector_type(8))) short short8;
typedef __attribute__((ext_vector_type(4))) float f32x4;

__device__ __forceinline__ unsigned short f2bf(float f) {
  union { float f; unsigned u; } x; x.f = f;
  unsigned r = x.u + 0x7fffu + ((x.u >> 16) & 1u);
  return (unsigned short)(r >> 16);
}
__device__ __forceinline__ float sigf(float x) { return 1.0f / (1.0f + __expf(-x)); }

// ---------------- feats fp32 -> bf16 copy ----------------
__global__ void k_convert(const float* __restrict__ in, unsigned short* __restrict__ out, int n4) {
  int i = blockIdx.x * blockDim.x + threadIdx.x;
  int stride = gridDim.x * blockDim.x;
  for (; i < n4; i += stride) {
    float4 f = ((const float4*)in)[i];
    ushort4 o;
    o.x = f2bf(f.x); o.y = f2bf(f.y); o.z = f2bf(f.z); o.w = f2bf(f.w);
    ((ushort4*)out)[i] = o;
  }
}

// ---------------- init logits with biases, frame with b_final ----------------
__global__ void k_init(float* __restrict__ wlog, float* __restrict__ rlog, float* __restrict__ frame,
                       const float* __restrict__ bl, const float* __restrict__ bg,
                       const float* __restrict__ bf) {
  int i = blockIdx.x * blockDim.x + threadIdx.x;
  const int n = MN * VN * CDIM;
  if (i < n) {
    int b = i % (VN * CDIM);
    wlog[i] = bl[b];
    rlog[i] = bg[b];
  }
  if (i < MN * NCLS) frame[i] = bf[i & 7];
}

// ---------------- split-K MFMA GEMM: out[m,v,c] += A[m,(v),k] * W[v][k,c] ----------------
// grid: (ksplit=16, cblk=8, v=6), block 256 (4 waves; wave = 16 c-columns, all 160 m rows)
__global__ __launch_bounds__(256) void k_gemm(
    const unsigned short* __restrict__ A, const float* __restrict__ Wg,
    float* __restrict__ outL, int a_row_stride, int a_v_stride, long long w_v_stride) {
  const int lane = threadIdx.x & 63;
  const int wv = threadIdx.x >> 6;
  const int v = blockIdx.z;
  const int cbase = blockIdx.y * 64 + wv * 16;
  const int l15 = lane & 15;
  const int kg = lane >> 4;                   // 0..3
  const int kstart = blockIdx.x * (49 * 32);  // 16 chunks * 1568 = 25088

  const unsigned short* Ap = A + (size_t)v * a_v_stride + (size_t)l15 * a_row_stride + kstart + kg * 8;
  const float* Wp = Wg + (size_t)v * w_v_stride + (size_t)(kstart + kg * 8) * CDIM + cbase + l15;

  f32x4 acc[10];
#pragma unroll
  for (int i = 0; i < 10; ++i) acc[i] = (f32x4)(0.0f);

  for (int s = 0; s < 49; ++s) {
    const float* wp = Wp + (size_t)s * (32 * CDIM);
    short8 bfrag;
#pragma unroll
    for (int j = 0; j < 8; ++j) bfrag[j] = (short)f2bf(wp[(size_t)j * CDIM]);
    const unsigned short* ap = Ap + s * 32;
#pragma unroll
    for (int mt = 0; mt < 10; ++mt) {
      short8 afrag = *(const short8*)(ap + (size_t)mt * 16 * a_row_stride);
      acc[mt] = __builtin_amdgcn_mfma_f32_16x16x32_bf16(afrag, bfrag, acc[mt], 0, 0, 0);
    }
  }
  const int c = cbase + l15;
#pragma unroll
  for (int mt = 0; mt < 10; ++mt) {
#pragma unroll
    for (int i = 0; i < 4; ++i) {
      int m = mt * 16 + kg * 4 + i;  // D row = (lane>>4)*4 + reg
      atomicAdd(&outL[(size_t)m * (VN * CDIM) + v * CDIM + c], acc[mt][i]);
    }
  }
}

// ---------------- w = sigmoid(logit); w_norm = w / sum_c(w) ----------------
__global__ void k_wnorm(const float* __restrict__ logit, float* __restrict__ w,
                        float* __restrict__ wn) {
  int v = blockIdx.x, m = blockIdx.y;
  size_t base = (size_t)(m * VN + v) * CDIM;
  int t = threadIdx.x;
  float s0 = sigf(logit[base + t]), s1 = sigf(logit[base + t + 256]);
  w[base + t] = s0; w[base + t + 256] = s1;
  __shared__ float red[256];
  red[t] = s0 + s1;
  __syncthreads();
  for (int o = 128; o > 0; o >>= 1) { if (t < o) red[t] += red[t + o]; __syncthreads(); }
  float inv = 1.0f / red[0];
  wn[base + t] = s0 * inv; wn[base + t + 256] = s1 * inv;
}

// ---------------- fw = w * sigmoid(rlogit); fw_norm = fw / sum_c(fw) ----------------
__global__ void k_fwnorm(const float* __restrict__ rlogit, const float* __restrict__ w,
                         float* __restrict__ fwn) {
  int v = blockIdx.x, m = blockIdx.y;
  size_t base = (size_t)(m * VN + v) * CDIM;
  int t = threadIdx.x;
  float f0 = w[base + t] * sigf(rlogit[base + t]);
  float f1 = w[base + t + 256] * sigf(rlogit[base + t + 256]);
  __shared__ float red[256];
  red[t] = f0 + f1;
  __syncthreads();
  for (int o = 128; o > 0; o >>= 1) { if (t < o) red[t] += red[t + o]; __syncthreads(); }
  float inv = 1.0f / red[0];
  fwn[base + t] = f0 * inv; fwn[base + t + 256] = f1 * inv;
}

// ---------------- weighted view-aggregation, fused with W_final contribution ----------------
// val[m,c,hw] = sum_v feats[m,v,c,hw] * wn[m,v,c]
// if aggb: store bf16(val) as agg_flat[m, c*49+hw]
// frame[m,n] += sum_{c,hw} val * W_final[wf_off + c*49+hw, n]
__global__ void k_aggregate(const float* __restrict__ feats, const float* __restrict__ wn,
                            unsigned short* __restrict__ aggb, const float* __restrict__ Wf,
                            float* __restrict__ frame, int wf_off) {
  int m = blockIdx.y;
  int cbase = blockIdx.x * 64;
  int t = threadIdx.x;
  float p[8] = {0, 0, 0, 0, 0, 0, 0, 0};
  for (int idx = t; idx < 64 * HWN; idx += 256) {
    int cl = idx / HWN;
    int hw = idx - cl * HWN;
    int c = cbase + cl;
    float val = 0.0f;
#pragma unroll
    for (int v = 0; v < VN; ++v)
      val += feats[(((size_t)m * VN + v) * CDIM + c) * HWN + hw] * wn[((size_t)m * VN + v) * CDIM + c];
    if (aggb) aggb[(size_t)m * F_LOC + c * HWN + hw] = f2bf(val);
    const float* wr = Wf + ((size_t)wf_off + c * HWN + hw) * NCLS;
#pragma unroll
    for (int n = 0; n < NCLS; ++n) p[n] += val * wr[n];
  }
  __shared__ float red[256];
  for (int n = 0; n < NCLS; ++n) {
    red[t] = p[n];
    __syncthreads();
    for (int o = 128; o > 0; o >>= 1) { if (t < o) red[t] += red[t + o]; __syncthreads(); }
    if (t == 0) atomicAdd(&frame[m * NCLS + n], red[0]);
    __syncthreads();
  }
}

// ---------------- out[b,n] = b_time[n] + sum_k frame[b,k] * W_time[k,n] ----------------
__global__ void k_out(const float* __restrict__ frame, const float* __restrict__ Wt,
                      const float* __restrict__ bt, float* __restrict__ out) {
  int t = threadIdx.x;  // 64
  int b = t >> 3, n = t & 7;
  float acc = bt[n];
  for (int k = 0; k < MN; ++k) acc += frame[b * MN + k] * Wt[k * NCLS + n];
  out[t] = acc;
}

extern "C" void kernel_launch(void* const* d_in, const int* in_sizes, int n_in,
                              void* d_out, int out_size, void* d_ws, size_t ws_size,
                              hipStream_t stream) {
  const float* feats    = (const float*)d_in[0];
  const float* W_local  = (const float*)d_in[1];
  const float* b_local  = (const float*)d_in[2];
  const float* W_global = (const float*)d_in[3];
  const float* b_global = (const float*)d_in[4];
  const float* W_final  = (const float*)d_in[5];
  const float* b_final  = (const float*)d_in[6];
  const float* W_time   = (const float*)d_in[7];
  const float* b_time   = (const float*)d_in[8];
  float* out = (float*)d_out;

  char* ws = (char*)d_ws;
  size_t off = 0;
  unsigned short* feats_bf = (unsigned short*)(ws + off); off += (size_t)MN * VN * F_LOC * 2;  // 48.2 MB
  unsigned short* agg_bf   = (unsigned short*)(ws + off); off += (size_t)MN * F_LOC * 2;       // 8 MB
  float* wlog   = (float*)(ws + off); off += (size_t)MN * VN * CDIM * 4;
  float* rlog   = (float*)(ws + off); off += (size_t)MN * VN * CDIM * 4;
  float* wbuf   = (float*)(ws + off); off += (size_t)MN * VN * CDIM * 4;
  float* wnorm  = (float*)(ws + off); off += (size_t)MN * VN * CDIM * 4;
  float* fwnorm = (float*)(ws + off); off += (size_t)MN * VN * CDIM * 4;
  float* frame  = (float*)(ws + off); off += 8192;

  const int NFEATS = MN * VN * F_LOC;  // 24,084,480

  k_convert<<<4096, 256, 0, stream>>>(feats, feats_bf, NFEATS / 4);
  k_init<<<(MN * VN * CDIM + 255) / 256, 256, 0, stream>>>(wlog, rlog, frame, b_local, b_global, b_final);

  dim3 gg(16, 8, 6);
  // w logits: A = feats_bf (row stride V*F, v stride F), W = W_local
  k_gemm<<<gg, 256, 0, stream>>>(feats_bf, W_local, wlog, VN * F_LOC, F_LOC, (long long)F_LOC * CDIM);
  k_wnorm<<<dim3(6, 160), 256, 0, stream>>>(wlog, wbuf, wnorm);
  // agg (+ its W_final rows [F_LOC, 2F_LOC) contribution to frame), store agg as bf16
  k_aggregate<<<dim3(8, 160), 256, 0, stream>>>(feats, wnorm, agg_bf, W_final, frame, F_LOC);
  // r logits, feats part: W_global rows [0, F_LOC)
  k_gemm<<<gg, 256, 0, stream>>>(feats_bf, W_global, rlog, VN * F_LOC, F_LOC, (long long)2 * F_LOC * CDIM);
  // r logits, agg part: W_global rows [F_LOC, 2F_LOC)
  k_gemm<<<gg, 256, 0, stream>>>(agg_bf, W_global + (size_t)F_LOC * CDIM, rlog, F_LOC, 0,
                                 (long long)2 * F_LOC * CDIM);
  k_fwnorm<<<dim3(6, 160), 256, 0, stream>>>(rlog, wbuf, fwnorm);
  // refined (never materialized): only its W_final rows [0, F_LOC) contribution to frame
  k_aggregate<<<dim3(8, 160), 256, 0, stream>>>(feats, fwnorm, nullptr, W_final, frame, 0);
  k_out<<<1, 64, 0, stream>>>(frame, W_time, b_time, out);
}

// Round 2
// 652.223 us; speedup vs baseline: 1.3110x; 1.3110x over previous
//
#include <hip/hip_runtime.h>

#define F_LOC 25088
#define CDIM 512
#define VN 6
#define MN 160      // B*T
#define HWN 49
#define NCLS 8
#define KSPLIT 16
#define KCHUNK 1568  // F_LOC / KSPLIT
#define NSTEP 49     // KCHUNK / 32

typedef __attribute__((ext_vector_type(8))) short short8;
typedef __attribute__((ext_vector_type(4))) float f32x4;
typedef unsigned short u16;

__device__ __forceinline__ u16 f2bf(float f) {
  union { float f; unsigned u; } x; x.f = f;
  unsigned r = x.u + 0x7fffu + ((x.u >> 16) & 1u);
  return (u16)(r >> 16);
}
__device__ __forceinline__ float sigf(float x) { return 1.0f / (1.0f + __expf(-x)); }

// ---------------- feats fp32 -> bf16 copy ----------------
__global__ void k_convert(const float* __restrict__ in, u16* __restrict__ out, int n4) {
  int i = blockIdx.x * blockDim.x + threadIdx.x;
  int stride = gridDim.x * blockDim.x;
  for (; i < n4; i += stride) {
    float4 f = ((const float4*)in)[i];
    ushort4 o;
    o.x = f2bf(f.x); o.y = f2bf(f.y); o.z = f2bf(f.z); o.w = f2bf(f.w);
    ((ushort4*)out)[i] = o;
  }
}

// ---------------- init frame with b_final ----------------
__global__ void k_initframe(float* __restrict__ frame, const float* __restrict__ bf) {
  int i = blockIdx.x * blockDim.x + threadIdx.x;
  if (i < MN * NCLS) frame[i] = bf[i & 7];
}

// ---------------- split-K MFMA GEMM, LDS-staged A, partial outputs ----------------
// 768 blocks of 256. bid = g + cb*96 where g=(v,ks); the 8 cb-blocks sharing an
// A chunk have the same bid%8 -> same XCD -> A read from HBM once, L2 hits after.
// part[(ks+slot_off)][m][v*512+c] = sum over this k-chunk (no atomics).
__global__ __launch_bounds__(256) void k_gemm(
    const u16* __restrict__ A, const float* __restrict__ Wg, float* __restrict__ part,
    int a_row_stride, int a_v_stride, long long w_v_stride, int slot_off) {
  __shared__ u16 lds[160 * 40];  // 12.8 KB, k-stride padded 32->40 (80B rows)

  const int bid = blockIdx.x;
  const int g = bid % 96;
  const int cb = bid / 96;       // 0..7
  const int v = g / KSPLIT;
  const int ks = g % KSPLIT;
  const int t = threadIdx.x;
  const int lane = t & 63;
  const int wv = t >> 6;
  const int l15 = lane & 15;
  const int kg = lane >> 4;      // 0..3
  const int kbase = ks * KCHUNK;

  const u16* Ab = A + (size_t)v * a_v_stride + kbase;
  const float* Wp = Wg + (size_t)v * w_v_stride + (size_t)kbase * CDIM + cb * 64 + wv * 16 + l15;

  f32x4 acc[10];
#pragma unroll
  for (int i = 0; i < 10; ++i) acc[i] = (f32x4)(0.0f);

  for (int s = 0; s < NSTEP; ++s) {
    // issue B loads early (independent of LDS)
    const float* wp = Wp + (size_t)(s * 32 + kg * 8) * CDIM;
    float bv[8];
#pragma unroll
    for (int j = 0; j < 8; ++j) bv[j] = wp[(size_t)j * CDIM];

    // stage A[160][32] -> LDS: 640 chunks of 16B, fully coalesced per row
    uint4 av[3];
#pragma unroll
    for (int p = 0; p < 3; ++p) {
      int i = t + p * 256;
      if (i < 640) {
        int row = i >> 2, q = i & 3;
        av[p] = *(const uint4*)(Ab + (size_t)row * a_row_stride + s * 32 + q * 8);
      }
    }
    if (s) __syncthreads();  // prior iteration's LDS reads done before overwrite
#pragma unroll
    for (int p = 0; p < 3; ++p) {
      int i = t + p * 256;
      if (i < 640) {
        int row = i >> 2, q = i & 3;
        *(uint4*)(&lds[row * 40 + q * 8]) = av[p];
      }
    }
    __syncthreads();

    short8 bfrag;
#pragma unroll
    for (int j = 0; j < 8; ++j) bfrag[j] = (short)f2bf(bv[j]);
#pragma unroll
    for (int mt = 0; mt < 10; ++mt) {
      short8 af = *(const short8*)(&lds[(l15 + 16 * mt) * 40 + kg * 8]);
      acc[mt] = __builtin_amdgcn_mfma_f32_16x16x32_bf16(af, bfrag, acc[mt], 0, 0, 0);
    }
  }

  const int c = cb * 64 + wv * 16 + l15;
  float* op = part + ((size_t)(ks + slot_off) * MN) * (VN * CDIM) + (size_t)v * CDIM + c;
#pragma unroll
  for (int mt = 0; mt < 10; ++mt)
#pragma unroll
    for (int i = 0; i < 4; ++i) {
      int m = mt * 16 + kg * 4 + i;  // D row = (lane>>4)*4 + reg
      op[(size_t)m * (VN * CDIM)] = acc[mt][i];
    }
}

// ---------------- reduce partials + bias, w = sigmoid, w_norm = w/sum_c ----------------
__global__ void k_wnorm(const float* __restrict__ part, const float* __restrict__ bias,
                        float* __restrict__ w, float* __restrict__ wn, int nslot) {
  int v = blockIdx.x, m = blockIdx.y, t = threadIdx.x;
  const size_t slot_stride = (size_t)MN * VN * CDIM;
  size_t base = (size_t)m * (VN * CDIM) + v * CDIM;
  float s0 = bias[v * CDIM + t], s1 = bias[v * CDIM + t + 256];
  for (int j = 0; j < nslot; ++j) {
    s0 += part[j * slot_stride + base + t];
    s1 += part[j * slot_stride + base + t + 256];
  }
  s0 = sigf(s0); s1 = sigf(s1);
  w[base + t] = s0; w[base + t + 256] = s1;
  __shared__ float red[256];
  red[t] = s0 + s1;
  __syncthreads();
  for (int o = 128; o > 0; o >>= 1) { if (t < o) red[t] += red[t + o]; __syncthreads(); }
  float inv = 1.0f / red[0];
  wn[base + t] = s0 * inv; wn[base + t + 256] = s1 * inv;
}

// ---------------- fw = w * sigmoid(rlogit); fw_norm ----------------
__global__ void k_fwnorm(const float* __restrict__ part, const float* __restrict__ bias,
                         const float* __restrict__ w, float* __restrict__ fwn, int nslot) {
  int v = blockIdx.x, m = blockIdx.y, t = threadIdx.x;
  const size_t slot_stride = (size_t)MN * VN * CDIM;
  size_t base = (size_t)m * (VN * CDIM) + v * CDIM;
  float s0 = bias[v * CDIM + t], s1 = bias[v * CDIM + t + 256];
  for (int j = 0; j < nslot; ++j) {
    s0 += part[j * slot_stride + base + t];
    s1 += part[j * slot_stride + base + t + 256];
  }
  float f0 = w[base + t] * sigf(s0);
  float f1 = w[base + t + 256] * sigf(s1);
  __shared__ float red[256];
  red[t] = f0 + f1;
  __syncthreads();
  for (int o = 128; o > 0; o >>= 1) { if (t < o) red[t] += red[t + o]; __syncthreads(); }
  float inv = 1.0f / red[0];
  fwn[base + t] = f0 * inv; fwn[base + t + 256] = f1 * inv;
}

// ---------------- weighted view-aggregation, fused with W_final contribution ----------------
__global__ void k_aggregate(const float* __restrict__ feats, const float* __restrict__ wn,
                            u16* __restrict__ aggb, const float* __restrict__ Wf,
                            float* __restrict__ frame, int wf_off) {
  int m = blockIdx.y;
  int cbase = blockIdx.x * 64;
  int t = threadIdx.x;
  float p[8] = {0, 0, 0, 0, 0, 0, 0, 0};
  for (int idx = t; idx < 64 * HWN; idx += 256) {
    int cl = idx / HWN;
    int hw = idx - cl * HWN;
    int c = cbase + cl;
    float val = 0.0f;
#pragma unroll
    for (int v = 0; v < VN; ++v)
      val += feats[(((size_t)m * VN + v) * CDIM + c) * HWN + hw] * wn[((size_t)m * VN + v) * CDIM + c];
    if (aggb) aggb[(size_t)m * F_LOC + c * HWN + hw] = f2bf(val);
    const float* wr = Wf + ((size_t)wf_off + c * HWN + hw) * NCLS;
#pragma unroll
    for (int n = 0; n < NCLS; ++n) p[n] += val * wr[n];
  }
  __shared__ float red[256];
  for (int n = 0; n < NCLS; ++n) {
    red[t] = p[n];
    __syncthreads();
    for (int o = 128; o > 0; o >>= 1) { if (t < o) red[t] += red[t + o]; __syncthreads(); }
    if (t == 0) atomicAdd(&frame[m * NCLS + n], red[0]);
    __syncthreads();
  }
}

// ---------------- out[b,n] = b_time[n] + sum_k frame[b,k] * W_time[k,n] ----------------
__global__ void k_out(const float* __restrict__ frame, const float* __restrict__ Wt,
                      const float* __restrict__ bt, float* __restrict__ out) {
  int t = threadIdx.x;  // 64
  int b = t >> 3, n = t & 7;
  float acc = bt[n];
  for (int k = 0; k < MN; ++k) acc += frame[b * MN + k] * Wt[k * NCLS + n];
  out[t] = acc;
}

extern "C" void kernel_launch(void* const* d_in, const int* in_sizes, int n_in,
                              void* d_out, int out_size, void* d_ws, size_t ws_size,
                              hipStream_t stream) {
  const float* feats    = (const float*)d_in[0];
  const float* W_local  = (const float*)d_in[1];
  const float* b_local  = (const float*)d_in[2];
  const float* W_global = (const float*)d_in[3];
  const float* b_global = (const float*)d_in[4];
  const float* W_final  = (const float*)d_in[5];
  const float* b_final  = (const float*)d_in[6];
  const float* W_time   = (const float*)d_in[7];
  const float* b_time   = (const float*)d_in[8];
  float* out = (float*)d_out;

  char* ws = (char*)d_ws;
  size_t off = 0;
  u16* feats_bf = (u16*)(ws + off); off += (size_t)MN * VN * F_LOC * 2;        // 48.2 MB
  u16* agg_bf   = (u16*)(ws + off); off += (size_t)MN * F_LOC * 2;             // 8 MB
  float* wpart  = (float*)(ws + off); off += (size_t)KSPLIT * MN * VN * CDIM * 4;      // 31.5 MB
  float* rpart  = (float*)(ws + off); off += (size_t)2 * KSPLIT * MN * VN * CDIM * 4;  // 63 MB
  float* wbuf   = (float*)(ws + off); off += (size_t)MN * VN * CDIM * 4;
  float* wnorm  = (float*)(ws + off); off += (size_t)MN * VN * CDIM * 4;
  float* fwnorm = (float*)(ws + off); off += (size_t)MN * VN * CDIM * 4;
  float* frame  = (float*)(ws + off); off += 8192;

  const int NFEATS = MN * VN * F_LOC;

  k_convert<<<4096, 256, 0, stream>>>(feats, feats_bf, NFEATS / 4);
  k_initframe<<<(MN * NCLS + 255) / 256, 256, 0, stream>>>(frame, b_final);

  // w logits
  k_gemm<<<768, 256, 0, stream>>>(feats_bf, W_local, wpart, VN * F_LOC, F_LOC,
                                  (long long)F_LOC * CDIM, 0);
  k_wnorm<<<dim3(6, 160), 256, 0, stream>>>(wpart, b_local, wbuf, wnorm, KSPLIT);
  // agg (+ W_final rows [F_LOC, 2F_LOC) -> frame), store agg as bf16
  k_aggregate<<<dim3(8, 160), 256, 0, stream>>>(feats, wnorm, agg_bf, W_final, frame, F_LOC);
  // r logits, feats part
  k_gemm<<<768, 256, 0, stream>>>(feats_bf, W_global, rpart, VN * F_LOC, F_LOC,
                                  (long long)2 * F_LOC * CDIM, 0);
  // r logits, agg part (A row stride F_LOC, no v stride) -> slots 16..31
  k_gemm<<<768, 256, 0, stream>>>(agg_bf, W_global + (size_t)F_LOC * CDIM, rpart, F_LOC, 0,
                                  (long long)2 * F_LOC * CDIM, KSPLIT);
  k_fwnorm<<<dim3(6, 160), 256, 0, stream>>>(rpart, b_global, wbuf, fwnorm, 2 * KSPLIT);
  // refined contribution (W_final rows [0, F_LOC)) -> frame
  k_aggregate<<<dim3(8, 160), 256, 0, stream>>>(feats, fwnorm, nullptr, W_final, frame, 0);
  k_out<<<1, 64, 0, stream>>>(frame, W_time, b_time, out);
}

// Round 3
// 406.190 us; speedup vs baseline: 2.1051x; 1.6057x over previous
//
#include <hip/hip_runtime.h>

#define F_LOC 25088
#define CDIM 512
#define VN 6
#define MN 160      // B*T
#define HWN 49
#define NCLS 8
#define KSPLIT 16
#define KCHUNK 1568  // F_LOC / KSPLIT
#define NSTEP 49     // KCHUNK / 32
#define ARS (VN * F_LOC)

typedef __attribute__((ext_vector_type(8))) short short8;
typedef __attribute__((ext_vector_type(4))) float f32x4;
typedef unsigned short u16;

__device__ __forceinline__ u16 f2bf(float f) {
  union { float f; unsigned u; } x; x.f = f;
  unsigned r = x.u + 0x7fffu + ((x.u >> 16) & 1u);
  return (u16)(r >> 16);
}
__device__ __forceinline__ float sigf(float x) { return 1.0f / (1.0f + __expf(-x)); }

__global__ void k_initframe(float* __restrict__ frame, const float* __restrict__ bf) {
  int i = blockIdx.x * blockDim.x + threadIdx.x;
  if (i < MN * NCLS) frame[i] = bf[i & 7];
}

// ---------------- GEMM core: one (v,ks,cb) chunk, A fp32 -> bf16 staged in LDS ----------------
// Double-buffered LDS, ONE barrier per k-step; A+B for step s+1 prefetched right
// after the barrier of step s (a full step of slack hides HBM/L2 latency).
__device__ __forceinline__ void gemm_core(
    const float* __restrict__ Ab, int a_rs,      // A chunk base (fp32), row stride
    const float* __restrict__ Wp,                // W + lane's c column
    float* __restrict__ op,                      // out + lane's c column, stride m*3072
    u16* __restrict__ lds, int t) {
  const int lane = t & 63;
  const int l15 = lane & 15;
  const int kg = lane >> 4;

  f32x4 acc[10];
#pragma unroll
  for (int i = 0; i < 10; ++i) acc[i] = (f32x4)(0.0f);

  float4 areg[5];
  float bv[8], bvn[8];
  // prefetch step 0: A tile 160x32 fp32 = 1280 float4, 5 per thread
#pragma unroll
  for (int p = 0; p < 5; ++p) {
    int i = t + p * 256, row = i >> 3, q = i & 7;
    areg[p] = *(const float4*)(Ab + (size_t)row * a_rs + q * 4);
  }
#pragma unroll
  for (int j = 0; j < 8; ++j) bv[j] = Wp[(size_t)(kg * 8 + j) * CDIM];

  for (int s = 0; s < NSTEP; ++s) {
    u16* buf = lds + (s & 1) * 6400;
    // stage A(s): convert fp32->bf16, write 8B per chunk; rows padded to 40 u16
#pragma unroll
    for (int p = 0; p < 5; ++p) {
      int i = t + p * 256, row = i >> 3, q = i & 7;
      ushort4 o;
      o.x = f2bf(areg[p].x); o.y = f2bf(areg[p].y);
      o.z = f2bf(areg[p].z); o.w = f2bf(areg[p].w);
      *(ushort4*)(buf + row * 40 + q * 4) = o;
    }
    __syncthreads();
    if (s < NSTEP - 1) {
#pragma unroll
      for (int p = 0; p < 5; ++p) {
        int i = t + p * 256, row = i >> 3, q = i & 7;
        areg[p] = *(const float4*)(Ab + (size_t)row * a_rs + (s + 1) * 32 + q * 4);
      }
#pragma unroll
      for (int j = 0; j < 8; ++j) bvn[j] = Wp[(size_t)((s + 1) * 32 + kg * 8 + j) * CDIM];
    }
    short8 bfrag;
#pragma unroll
    for (int j = 0; j < 8; ++j) bfrag[j] = (short)f2bf(bv[j]);
#pragma unroll
    for (int mt = 0; mt < 10; ++mt) {
      short8 af = *(const short8*)(buf + (l15 + 16 * mt) * 40 + kg * 8);
      acc[mt] = __builtin_amdgcn_mfma_f32_16x16x32_bf16(af, bfrag, acc[mt], 0, 0, 0);
    }
#pragma unroll
    for (int j = 0; j < 8; ++j) bv[j] = bvn[j];
  }
#pragma unroll
  for (int mt = 0; mt < 10; ++mt)
#pragma unroll
    for (int i = 0; i < 4; ++i) {
      int m = mt * 16 + kg * 4 + i;  // D row = (lane>>4)*4 + reg
      op[(size_t)m * (VN * CDIM)] = acc[mt][i];
    }
}

// ---------------- merged GEMM1+2: sub=0 -> W_local/wpart, sub=1 -> W_global[0:F]/rpart ----------------
// bid%8 invariant across cb and sub -> all blocks sharing an A chunk on one XCD.
__global__ __launch_bounds__(256, 3) void k_gemm12(
    const float* __restrict__ feats, const float* __restrict__ Wl,
    const float* __restrict__ Wgl, float* __restrict__ wpart, float* __restrict__ rpart) {
  __shared__ u16 lds[2 * 6400];  // 25.6 KB
  int bid = blockIdx.x;
  int sub = bid >= 768 ? 1 : 0;
  int b = bid - sub * 768;
  int g = b % 96, cb = b / 96;
  int v = g / KSPLIT, ks = g % KSPLIT;
  int t = threadIdx.x;
  int wv = t >> 6, l15 = t & 15;
  int c = cb * 64 + wv * 16 + l15;
  const float* Ab = feats + (size_t)v * F_LOC + (size_t)ks * KCHUNK;
  const float* W = sub ? Wgl : Wl;
  long long wvs = sub ? (long long)2 * F_LOC * CDIM : (long long)F_LOC * CDIM;
  const float* Wp = W + (size_t)v * wvs + (size_t)ks * KCHUNK * CDIM + c;
  float* op = (sub ? rpart : wpart) + (size_t)ks * MN * (VN * CDIM) + (size_t)v * CDIM + c;
  gemm_core(Ab, ARS, Wp, op, lds, t);
}

// ---------------- GEMM3: A = agg (fp32, shared across v), W_global rows [F_LOC, 2F) ----------------
__global__ __launch_bounds__(256, 3) void k_gemm3(
    const float* __restrict__ agg, const float* __restrict__ Wgl, float* __restrict__ rpart) {
  __shared__ u16 lds[2 * 6400];
  int b = blockIdx.x;
  int g = b % 96, cb = b / 96;
  int v = g / KSPLIT, ks = g % KSPLIT;
  int t = threadIdx.x;
  int wv = t >> 6, l15 = t & 15;
  int c = cb * 64 + wv * 16 + l15;
  const float* Ab = agg + (size_t)ks * KCHUNK;
  const float* Wp = Wgl + (size_t)F_LOC * CDIM + (size_t)v * (2ll * F_LOC * CDIM) +
                    (size_t)ks * KCHUNK * CDIM + c;
  float* op = rpart + (size_t)(KSPLIT + ks) * MN * (VN * CDIM) + (size_t)v * CDIM + c;
  gemm_core(Ab, F_LOC, Wp, op, lds, t);
}

// ---------------- reduce partials + bias, w = sigmoid, w_norm = w/sum_c ----------------
__global__ void k_wnorm(const float* __restrict__ part, const float* __restrict__ bias,
                        float* __restrict__ w, float* __restrict__ wn, int nslot) {
  int v = blockIdx.x, m = blockIdx.y, t = threadIdx.x;
  const size_t slot_stride = (size_t)MN * VN * CDIM;
  size_t base = (size_t)m * (VN * CDIM) + v * CDIM;
  float s0 = bias[v * CDIM + t], s1 = bias[v * CDIM + t + 256];
  for (int j = 0; j < nslot; ++j) {
    s0 += part[j * slot_stride + base + t];
    s1 += part[j * slot_stride + base + t + 256];
  }
  s0 = sigf(s0); s1 = sigf(s1);
  w[base + t] = s0; w[base + t + 256] = s1;
  __shared__ float red[256];
  red[t] = s0 + s1;
  __syncthreads();
  for (int o = 128; o > 0; o >>= 1) { if (t < o) red[t] += red[t + o]; __syncthreads(); }
  float inv = 1.0f / red[0];
  wn[base + t] = s0 * inv; wn[base + t + 256] = s1 * inv;
}

__global__ void k_fwnorm(const float* __restrict__ part, const float* __restrict__ bias,
                         const float* __restrict__ w, float* __restrict__ fwn, int nslot) {
  int v = blockIdx.x, m = blockIdx.y, t = threadIdx.x;
  const size_t slot_stride = (size_t)MN * VN * CDIM;
  size_t base = (size_t)m * (VN * CDIM) + v * CDIM;
  float s0 = bias[v * CDIM + t], s1 = bias[v * CDIM + t + 256];
  for (int j = 0; j < nslot; ++j) {
    s0 += part[j * slot_stride + base + t];
    s1 += part[j * slot_stride + base + t + 256];
  }
  float f0 = w[base + t] * sigf(s0);
  float f1 = w[base + t + 256] * sigf(s1);
  __shared__ float red[256];
  red[t] = f0 + f1;
  __syncthreads();
  for (int o = 128; o > 0; o >>= 1) { if (t < o) red[t] += red[t + o]; __syncthreads(); }
  float inv = 1.0f / red[0];
  fwn[base + t] = f0 * inv; fwn[base + t + 256] = f1 * inv;
}

// ---------------- weighted view-aggregation, fused with W_final contribution ----------------
__global__ void k_aggregate(const float* __restrict__ feats, const float* __restrict__ wn,
                            float* __restrict__ aggf, const float* __restrict__ Wf,
                            float* __restrict__ frame, int wf_off) {
  int m = blockIdx.y;
  int cbase = blockIdx.x * 64;
  int t = threadIdx.x;
  float p[8] = {0, 0, 0, 0, 0, 0, 0, 0};
  for (int idx = t; idx < 64 * HWN; idx += 256) {
    int cl = idx / HWN;
    int hw = idx - cl * HWN;
    int c = cbase + cl;
    float val = 0.0f;
#pragma unroll
    for (int v = 0; v < VN; ++v)
      val += feats[(((size_t)m * VN + v) * CDIM + c) * HWN + hw] * wn[((size_t)m * VN + v) * CDIM + c];
    if (aggf) aggf[(size_t)m * F_LOC + c * HWN + hw] = val;
    const float* wr = Wf + ((size_t)wf_off + c * HWN + hw) * NCLS;
#pragma unroll
    for (int n = 0; n < NCLS; ++n) p[n] += val * wr[n];
  }
  __shared__ float red[256];
  for (int n = 0; n < NCLS; ++n) {
    red[t] = p[n];
    __syncthreads();
    for (int o = 128; o > 0; o >>= 1) { if (t < o) red[t] += red[t + o]; __syncthreads(); }
    if (t == 0) atomicAdd(&frame[m * NCLS + n], red[0]);
    __syncthreads();
  }
}

__global__ void k_out(const float* __restrict__ frame, const float* __restrict__ Wt,
                      const float* __restrict__ bt, float* __restrict__ out) {
  int t = threadIdx.x;  // 64
  int b = t >> 3, n = t & 7;
  float acc = bt[n];
  for (int k = 0; k < MN; ++k) acc += frame[b * MN + k] * Wt[k * NCLS + n];
  out[t] = acc;
}

extern "C" void kernel_launch(void* const* d_in, const int* in_sizes, int n_in,
                              void* d_out, int out_size, void* d_ws, size_t ws_size,
                              hipStream_t stream) {
  const float* feats    = (const float*)d_in[0];
  const float* W_local  = (const float*)d_in[1];
  const float* b_local  = (const float*)d_in[2];
  const float* W_global = (const float*)d_in[3];
  const float* b_global = (const float*)d_in[4];
  const float* W_final  = (const float*)d_in[5];
  const float* b_final  = (const float*)d_in[6];
  const float* W_time   = (const float*)d_in[7];
  const float* b_time   = (const float*)d_in[8];
  float* out = (float*)d_out;

  char* ws = (char*)d_ws;
  size_t off = 0;
  float* aggf   = (float*)(ws + off); off += (size_t)MN * F_LOC * 4;                   // 16 MB
  float* wpart  = (float*)(ws + off); off += (size_t)KSPLIT * MN * VN * CDIM * 4;      // 31.5 MB
  float* rpart  = (float*)(ws + off); off += (size_t)2 * KSPLIT * MN * VN * CDIM * 4;  // 63 MB
  float* wbuf   = (float*)(ws + off); off += (size_t)MN * VN * CDIM * 4;
  float* wnorm  = (float*)(ws + off); off += (size_t)MN * VN * CDIM * 4;
  float* fwnorm = (float*)(ws + off); off += (size_t)MN * VN * CDIM * 4;
  float* frame  = (float*)(ws + off); off += 8192;

  k_initframe<<<(MN * NCLS + 255) / 256, 256, 0, stream>>>(frame, b_final);

  // w logits + r logits (feats part) in one dispatch
  k_gemm12<<<1536, 256, 0, stream>>>(feats, W_local, W_global, wpart, rpart);
  k_wnorm<<<dim3(6, 160), 256, 0, stream>>>(wpart, b_local, wbuf, wnorm, KSPLIT);
  // agg (+ W_final rows [F_LOC, 2F_LOC) -> frame), store agg fp32
  k_aggregate<<<dim3(8, 160), 256, 0, stream>>>(feats, wnorm, aggf, W_final, frame, F_LOC);
  // r logits, agg part -> slots 16..31
  k_gemm3<<<768, 256, 0, stream>>>(aggf, W_global, rpart);
  k_fwnorm<<<dim3(6, 160), 256, 0, stream>>>(rpart, b_global, wbuf, fwnorm, 2 * KSPLIT);
  // refined contribution (W_final rows [0, F_LOC)) -> frame
  k_aggregate<<<dim3(8, 160), 256, 0, stream>>>(feats, fwnorm, nullptr, W_final, frame, 0);
  k_out<<<1, 64, 0, stream>>>(frame, W_time, b_time, out);
}